// Round 14
// baseline (79.589 us; speedup 1.0000x reference)
//
#include <hip/hip_runtime.h>
#include <hip/hip_bf16.h>

// Problem constants
#define Bq   4
#define Cc   64
#define Hh   160
#define Ww   160
#define HWp  (Hh * Ww)          // 25600
#define COUTc 64

typedef __attribute__((ext_vector_type(8))) _Float16 f16x8;
typedef __attribute__((ext_vector_type(4))) _Float16 f16x4;
typedef __attribute__((ext_vector_type(4))) float f32x4;
typedef __attribute__((ext_vector_type(2))) float f32x2;
typedef __attribute__((ext_vector_type(4))) int   int4v;

// ws layout (shorts, fp16 bit patterns):
//   wTbF  : 72 frags x 512  (main weights, fragment-major)
//           frag fidx = (tap*2+h)*4 + cg ; element l*8+j =
//           w[o=cg*16+(l&15)][c=h*32+(l>>4)*8+j][tap]
//   wToffF: 36 frags x 512  (offset weights, fragment-major)
//           frag fidx = (tap*2+h)*2 + g ; element l*8+j =
//           w_off[oc=g*16+(l&15)][c][tap]  (oc>=18 -> 0)
//   xcl   [b][y][x][c] : 4*25600*64 + 64 (zero pad pixel at end)
#define WTBF_SHORTS   (72 * 512)                    // 36864
#define WTOFFF_SHORTS (36 * 512)                    // 18432
#define XCL_OFS       (WTBF_SHORTS + WTOFFF_SHORTS) // 55296
#define XCL_PIX       ((size_t)Bq * HWp)            // zero pad pixel index
#define XCL_SHORTS    (XCL_PIX * 64 + 64)

// sm row stride: 72 shorts = 144 B — multiple of 16 B (ds_*_b128 alignment).
#define SMS 72

__device__ __forceinline__ short f2h(float f) {
    union { _Float16 h; short s; } v; v.h = (_Float16)f; return v.s;
}
__device__ __forceinline__ unsigned pk2h(float a, float b) {
    union { _Float16 h[2]; unsigned u; } v;
    v.h[0] = (_Float16)a; v.h[1] = (_Float16)b; return v.u;
}
__device__ __forceinline__ f16x8 vsplat(_Float16 v) {
    return (f16x8){v, v, v, v, v, v, v, v};
}

// ---------------------------------------------------------------------------
// Merged prep: [0,400) xcl image (fp16); [400,544) fragment-major weights;
// 544 zero pad.
// ---------------------------------------------------------------------------
__global__ __launch_bounds__(256) void prep_all(const float* __restrict__ x,
                                                const float* __restrict__ w,
                                                const float* __restrict__ w_off,
                                                short* __restrict__ ws) {
    int blk = blockIdx.x;
    int tid = threadIdx.x;
    if (blk < 400) {
        int g = blk * 256 + tid;             // pixel id
        int b = g / HWp, p = g - b * HWp;
        const float* xp = x + (size_t)b * Cc * HWp + p;
        short* op = ws + XCL_OFS + (size_t)g * 64;
#pragma unroll
        for (int cg = 0; cg < 8; ++cg) {
            unsigned d[4];
#pragma unroll
            for (int dj = 0; dj < 4; ++dj) {
                float f0 = xp[(size_t)(cg * 8 + 2 * dj) * HWp];
                float f1 = xp[(size_t)(cg * 8 + 2 * dj + 1) * HWp];
                d[dj] = pk2h(f0, f1);
            }
            *(int4v*)(op + cg * 8) = *(int4v*)d;
        }
    } else if (blk < 544) {
        int i = (blk - 400) * 256 + tid;
        if (i < WTBF_SHORTS) {
            int fidx = i >> 9, r = i & 511;
            int l = r >> 3, j = r & 7;
            int cg = fidx & 3, th = fidx >> 2;
            int tap = th >> 1, h = th & 1;
            int o = cg * 16 + (l & 15);
            int c = h * 32 + ((l >> 4) << 3) + j;
            ws[i] = f2h(w[o * 576 + c * 9 + tap]);
        }
        if (i < WTOFFF_SHORTS) {
            int fidx = i >> 9, r = i & 511;
            int l = r >> 3, j = r & 7;
            int g = fidx & 1, th = fidx >> 1;
            int tap = th >> 1, h = th & 1;
            int oc = g * 16 + (l & 15);
            int c = h * 32 + ((l >> 4) << 3) + j;
            float v = (oc < 18) ? w_off[oc * 576 + c * 9 + tap] : 0.f;
            ws[WTBF_SHORTS + i] = f2h(v);
        }
    } else {
        if (tid < 8)
            *(int4v*)((char*)(ws + XCL_OFS) + XCL_PIX * 128 + tid * 16) =
                (int4v){0, 0, 0, 0};
    }
}

// ---------------------------------------------------------------------------
// Sample NT taps, 4-deep corner-load pipeline (consume-then-refill).
// thread = (px = tid>>3, cg = tid&7), cb = cg*16 byte channel offset.
// ---------------------------------------------------------------------------
template<int T0, int NT>
__device__ __forceinline__ void sample_taps(const char* __restrict__ xclb,
                                            short (*__restrict__ sm)[32][SMS],
                                            const int4v (*__restrict__ linT)[9],
                                            const f16x4 (*__restrict__ wgtT)[9],
                                            int px, int cb) {
    int4v  liq[4];
    f16x4  wq[4];
    f16x8  stq[4][4];
    constexpr int PD = (NT < 4) ? NT : 4;
#pragma unroll
    for (int s = 0; s < PD; ++s) {
        liq[s] = linT[px][T0 + s];
        wq[s]  = wgtT[px][T0 + s];
#pragma unroll
        for (int c = 0; c < 4; ++c)
            stq[s][c] = *(const f16x8*)(xclb + liq[s][c] + cb);
    }
#pragma unroll
    for (int ti = 0; ti < NT; ++ti) {
        const int s = ti & 3;
        // consume FIRST ...
        f16x8 a = stq[s][0] * vsplat(wq[s][0]) + stq[s][1] * vsplat(wq[s][1])
                + stq[s][2] * vsplat(wq[s][2]) + stq[s][3] * vsplat(wq[s][3]);
        *(f16x8*)((char*)&sm[ti][px][0] + cb) = a;
        // ... then refill the freed slot for ti+4
        if (ti + 4 < NT) {
            liq[s] = linT[px][T0 + ti + 4];
            wq[s]  = wgtT[px][T0 + ti + 4];
#pragma unroll
            for (int c = 0; c < 4; ++c)
                stq[s][c] = *(const f16x8*)(xclb + liq[s][c] + cb);
        }
        __builtin_amdgcn_sched_barrier(0);
    }
}

// ---------------------------------------------------------------------------
// GEMM NT taps from sm; 2-deep DISTINCT-slot staging (prefetch slot (u+1)&1,
// consume slot u&1 — never aliases). wfb = wTbF + nhalf*1024 + l*8.
// ---------------------------------------------------------------------------
template<int T0, int NT>
__device__ __forceinline__ void gemm_taps(const short (*__restrict__ sm)[32][SMS],
                                          f32x4* acc, int px_t, int lg,
                                          const short* __restrict__ wfb) {
    f16x8 sa[2], s0[2], s1[2];
    sa[0] = *(const f16x8*)(&sm[0][px_t][lg * 8]);
    s0[0] = *(const f16x8*)(wfb + (T0 * 2) * 2048);
    s1[0] = *(const f16x8*)(wfb + (T0 * 2) * 2048 + 512);
#pragma unroll
    for (int u = 0; u < 2 * NT; ++u) {
        if (u + 1 < 2 * NT) {
            const int ti = (u + 1) >> 1, h = (u + 1) & 1, ns = (u + 1) & 1;
            sa[ns] = *(const f16x8*)(&sm[ti][px_t][h * 32 + lg * 8]);
            s0[ns] = *(const f16x8*)(wfb + ((T0 + ti) * 2 + h) * 2048);
            s1[ns] = *(const f16x8*)(wfb + ((T0 + ti) * 2 + h) * 2048 + 512);
        }
        __builtin_amdgcn_sched_barrier(0);
        const int cs = u & 1;
        acc[0] = __builtin_amdgcn_mfma_f32_16x16x32_f16(sa[cs], s0[cs], acc[0], 0, 0, 0);
        acc[1] = __builtin_amdgcn_mfma_f32_16x16x32_f16(sa[cs], s1[cs], acc[1], 0, 0, 0);
    }
}

// ---------------------------------------------------------------------------
// Fused kernel: 32-pixel tile; two K-halves; offbuf UNIONED into sm region
// (LDS 29.9 KB -> 5 blocks/CU). Deep staging + high occupancy combined.
// ---------------------------------------------------------------------------
__global__ __launch_bounds__(256, 5) void fused_cl(const short* __restrict__ ws,
                                                   const float* __restrict__ b_off,
                                                   const float* __restrict__ bias,
                                                   float* __restrict__ out) {
    __shared__ short smbuf[5][32][SMS]; // 23040 B; first 2560 B double as offbuf
    __shared__ int4v linT[32][9];       // byte offsets of 4 corners (4608 B)
    __shared__ f16x4 wgtT[32][9];       // bilinear weights, packed fp16 (2304 B)

    // offbuf overlays smbuf: written in phase 1, read in phase 2, dead before
    // the first sm write (phase 3a, after the phase-2 barrier).
    float (*offbuf)[20] = reinterpret_cast<float(*)[20]>(&smbuf[0][0][0]);

    int tid = threadIdx.x;
    int wid = tid >> 6;
    int l   = tid & 63;
    int lr  = l & 15;
    int lg  = l >> 4;
    int mhalf = wid >> 1;
    int nhalf = wid & 1;

    // XCD-aware swizzle: nwg = 3200, 3200 % 8 == 0 -> bijective
    int bid = blockIdx.x;
    int g_blk = (bid & 7) * 400 + (bid >> 3);

    int pix_base = g_blk * 32;
    int b   = pix_base / HWp;
    int rem = pix_base - b * HWp;
    int y   = rem / Ww;
    int x0  = rem - y * Ww;            // multiple of 32, row-aligned

    const short* wTbF   = ws;
    const short* wToffF = ws + WTBF_SHORTS;
    const char*  xclb   = (const char*)(ws + XCL_OFS) + (size_t)b * HWp * 128;
    const int zoff = (int)((Bq - b) * (size_t)HWp * 128);   // zero pad pixel

    // ---------------- Phase 1: offset GEMM (4-deep, consume-then-refill) --
    {
        int px_t1 = mhalf * 16 + lr;
        int xpix  = x0 + px_t1;
        int poff[9];
#pragma unroll
        for (int ty = 0; ty < 3; ++ty) {
#pragma unroll
            for (int tx = 0; tx < 3; ++tx) {
                int t  = ty * 3 + tx;
                int yy = y - 1 + ty;
                bool vy = (yy >= 0) && (yy < Hh);
                int yc = min(max(yy, 0), Hh - 1);
                int xx = xpix - 1 + tx;
                bool vx = (xx >= 0) && (xx < Ww);
                int xc = min(max(xx, 0), Ww - 1);
                poff[t] = (vy && vx) ? (yc * Ww + xc) * 128 : zoff;
            }
        }
        const short* wofr = wToffF + (size_t)nhalf * 512 + l * 8;
        f32x4 accA = {0.f, 0.f, 0.f, 0.f};
        f32x4 accB = {0.f, 0.f, 0.f, 0.f};
        f16x8 sA[4], sB[4];
#pragma unroll
        for (int u = 0; u < 4; ++u) {
            const int t = u >> 1, h = u & 1;
            sA[u] = *(const f16x8*)(xclb + poff[t] + lg * 16 + h * 64);
            sB[u] = *(const f16x8*)(wofr + u * 1024);
        }
#pragma unroll
        for (int u = 0; u < 18; ++u) {
            const int s = u & 3;
            if (u & 1)
                accB = __builtin_amdgcn_mfma_f32_16x16x32_f16(sA[s], sB[s], accB, 0, 0, 0);
            else
                accA = __builtin_amdgcn_mfma_f32_16x16x32_f16(sA[s], sB[s], accA, 0, 0, 0);
            if (u + 4 < 18) {
                const int un = u + 4, t = un >> 1, h = un & 1;
                sA[s] = *(const f16x8*)(xclb + poff[t] + lg * 16 + h * 64);
                sB[s] = *(const f16x8*)(wofr + un * 1024);
            }
            __builtin_amdgcn_sched_barrier(0);
        }
        int oc_row = nhalf * 16 + lr;
        if (oc_row < 18) {
            float bv = b_off[oc_row];
#pragma unroll
            for (int j = 0; j < 4; ++j)
                offbuf[mhalf * 16 + lg * 4 + j][oc_row] = accA[j] + accB[j] + bv;
        }
    }
    __syncthreads();

    // ---------------- Phase 2: shared bilinear tables ----------------
    for (int i = tid; i < 288; i += 256) {
        int px = i / 9, tap = i - px * 9;
        int ty = tap / 3, tx = tap - ty * 3;
        f32x2 d2 = *(const f32x2*)&offbuf[px][2 * tap];
        float py  = (float)(y - 1 + ty) + d2[0];
        float pxf = (float)(x0 + px - 1 + tx) + d2[1];
        float fy = floorf(py), fx = floorf(pxf);
        float ly = py - fy, lx = pxf - fx;
        int iy0 = (int)fy, ix0 = (int)fx;
        int iy1 = iy0 + 1, ix1 = ix0 + 1;
        bool vy0 = (iy0 >= 0) && (iy0 < Hh);
        bool vy1 = (iy1 >= 0) && (iy1 < Hh);
        bool vx0 = (ix0 >= 0) && (ix0 < Ww);
        bool vx1 = (ix1 >= 0) && (ix1 < Ww);
        int cy0 = min(max(iy0, 0), Hh - 1), cy1 = min(max(iy1, 0), Hh - 1);
        int cx0 = min(max(ix0, 0), Ww - 1), cx1 = min(max(ix1, 0), Ww - 1);
        int4v li;
        li[0] = (cy0 * Ww + cx0) * 128;
        li[1] = (cy0 * Ww + cx1) * 128;
        li[2] = (cy1 * Ww + cx0) * 128;
        li[3] = (cy1 * Ww + cx1) * 128;
        float w00 = (vy0 && vx0) ? (1.f - ly) * (1.f - lx) : 0.f;
        float w01 = (vy0 && vx1) ? (1.f - ly) * lx         : 0.f;
        float w10 = (vy1 && vx0) ? ly * (1.f - lx)         : 0.f;
        float w11 = (vy1 && vx1) ? ly * lx                 : 0.f;
        linT[px][tap] = li;
        wgtT[px][tap] = (f16x4){(_Float16)w00, (_Float16)w01,
                                (_Float16)w10, (_Float16)w11};
    }
    __syncthreads();

    // ---------------- Sample + GEMM, two K-halves ----------
    int px = tid >> 3;          // 0..31
    int cg = tid & 7;
    int cb = cg * 16;

    f32x4 acc[2];
    acc[0] = (f32x4){0.f, 0.f, 0.f, 0.f};
    acc[1] = (f32x4){0.f, 0.f, 0.f, 0.f};
    int px_t = mhalf * 16 + lr;
    const short* wfb = wTbF + (size_t)nhalf * 1024 + l * 8;

    // half 0: taps 0..4
    sample_taps<0, 5>(xclb, smbuf, linT, wgtT, px, cb);
    __syncthreads();
    gemm_taps<0, 5>(smbuf, acc, px_t, lg, wfb);
    __syncthreads();

    // half 1: taps 5..8
    sample_taps<5, 4>(xclb, smbuf, linT, wgtT, px, cb);
    __syncthreads();
    gemm_taps<5, 4>(smbuf, acc, px_t, lg, wfb);

    // ---------------- Epilogue ----------------
    float* obase = out + (size_t)b * COUTc * HWp + y * Ww + x0;
#pragma unroll
    for (int nt = 0; nt < 2; ++nt) {
        int o = nhalf * 32 + nt * 16 + lr;
        float bv = bias[o];
#pragma unroll
        for (int j = 0; j < 4; ++j)
            obase[(size_t)o * HWp + mhalf * 16 + lg * 4 + j] = acc[nt][j] + bv;
    }
}

// ---------------------------------------------------------------------------
extern "C" void kernel_launch(void* const* d_in, const int* in_sizes, int n_in,
                              void* d_out, int out_size, void* d_ws, size_t ws_size,
                              hipStream_t stream) {
    const float* x      = (const float*)d_in[0];
    const float* w_off  = (const float*)d_in[1];
    const float* b_off  = (const float*)d_in[2];
    const float* weight = (const float*)d_in[3];
    const float* bias   = (const float*)d_in[4];
    float* outp = (float*)d_out;
    short* ws   = (short*)d_ws;

    // 400 blocks xcl + 144 blocks weights + 1 block zero pad
    prep_all<<<545, 256, 0, stream>>>(x, weight, w_off, ws);

    int nblocks = (Bq * HWp) / 32;   // 3200 workgroups, 32 pixels each
    fused_cl<<<nblocks, 256, 0, stream>>>(ws, b_off, bias, outp);
}

// Round 15
// 52.011 us; speedup vs baseline: 1.5302x; 1.5302x over previous
//
#include <hip/hip_runtime.h>
#include <hip/hip_bf16.h>

// Problem constants
#define Bq   4
#define Cc   64
#define Hh   160
#define Ww   160
#define HWp  (Hh * Ww)          // 25600
#define COUTc 64

typedef __attribute__((ext_vector_type(8))) _Float16 f16x8;
typedef __attribute__((ext_vector_type(4))) _Float16 f16x4;
typedef __attribute__((ext_vector_type(4))) float f32x4;
typedef __attribute__((ext_vector_type(2))) float f32x2;
typedef __attribute__((ext_vector_type(4))) int   int4v;

// ws layout (shorts, fp16 bit patterns):
//   wTbF  : 72 frags x 512  (main weights, fragment-major)
//   wToffF: 36 frags x 512  (offset weights, fragment-major)
//   xcl   [b][y][x][c] : 4*25600*64 + 64 (zero pad pixel at end)
#define WTBF_SHORTS   (72 * 512)                    // 36864
#define WTOFFF_SHORTS (36 * 512)                    // 18432
#define XCL_OFS       (WTBF_SHORTS + WTOFFF_SHORTS) // 55296
#define XCL_PIX       ((size_t)Bq * HWp)            // zero pad pixel index
#define XCL_SHORTS    (XCL_PIX * 64 + 64)

// Halo: rows y-2..y+3 (6), cols x0-2..x0+33 (36), 72 shorts (144 B) per pixel.
#define HROWS 6
#define HCOLS 36
#define HPX   72                       // shorts per halo pixel
#define HROWS_STRIDE (HCOLS * HPX)     // 2592 shorts per halo row

__device__ __forceinline__ short f2h(float f) {
    union { _Float16 h; short s; } v; v.h = (_Float16)f; return v.s;
}
__device__ __forceinline__ unsigned pk2h(float a, float b) {
    union { _Float16 h[2]; unsigned u; } v;
    v.h[0] = (_Float16)a; v.h[1] = (_Float16)b; return v.u;
}
__device__ __forceinline__ f16x8 vsplat(_Float16 v) {
    return (f16x8){v, v, v, v, v, v, v, v};
}

// ---------------------------------------------------------------------------
// Merged prep (unchanged, validated): [0,400) xcl fp16 image; [400,544)
// fragment-major weights; 544 zero pad.
// ---------------------------------------------------------------------------
__global__ __launch_bounds__(256) void prep_all(const float* __restrict__ x,
                                                const float* __restrict__ w,
                                                const float* __restrict__ w_off,
                                                short* __restrict__ ws) {
    int blk = blockIdx.x;
    int tid = threadIdx.x;
    if (blk < 400) {
        int g = blk * 256 + tid;             // pixel id
        int b = g / HWp, p = g - b * HWp;
        const float* xp = x + (size_t)b * Cc * HWp + p;
        short* op = ws + XCL_OFS + (size_t)g * 64;
#pragma unroll
        for (int cg = 0; cg < 8; ++cg) {
            unsigned d[4];
#pragma unroll
            for (int dj = 0; dj < 4; ++dj) {
                float f0 = xp[(size_t)(cg * 8 + 2 * dj) * HWp];
                float f1 = xp[(size_t)(cg * 8 + 2 * dj + 1) * HWp];
                d[dj] = pk2h(f0, f1);
            }
            *(int4v*)(op + cg * 8) = *(int4v*)d;
        }
    } else if (blk < 544) {
        int i = (blk - 400) * 256 + tid;
        if (i < WTBF_SHORTS) {
            int fidx = i >> 9, r = i & 511;
            int l = r >> 3, j = r & 7;
            int cg = fidx & 3, th = fidx >> 2;
            int tap = th >> 1, h = th & 1;
            int o = cg * 16 + (l & 15);
            int c = h * 32 + ((l >> 4) << 3) + j;
            ws[i] = f2h(w[o * 576 + c * 9 + tap]);
        }
        if (i < WTOFFF_SHORTS) {
            int fidx = i >> 9, r = i & 511;
            int l = r >> 3, j = r & 7;
            int g = fidx & 1, th = fidx >> 1;
            int tap = th >> 1, h = th & 1;
            int oc = g * 16 + (l & 15);
            int c = h * 32 + ((l >> 4) << 3) + j;
            float v = (oc < 18) ? w_off[oc * 576 + c * 9 + tap] : 0.f;
            ws[WTBF_SHORTS + i] = f2h(v);
        }
    } else {
        if (tid < 8)
            *(int4v*)((char*)(ws + XCL_OFS) + XCL_PIX * 128 + tid * 16) =
                (int4v){0, 0, 0, 0};
    }
}

// ---------------------------------------------------------------------------
// Fused kernel: 32-pixel tile; LDS halo (all gathers become LDS reads);
// no sm tile; 3 barriers; B-streams 4-deep staged.
// ---------------------------------------------------------------------------
__global__ __launch_bounds__(256, 4) void fused_cl(const short* __restrict__ ws,
                                                   const float* __restrict__ b_off,
                                                   const float* __restrict__ bias,
                                                   float* __restrict__ out) {
    __shared__ short halo_s[HROWS * HCOLS * HPX];  // 31104 B
    __shared__ float offbuf[32][20];               // 2560 B
    __shared__ int   hofT[32][9];                  // 1152 B (short-offset, <0 = fallback)
    __shared__ f16x4 wgtT[32][9];                  // 2304 B
    __shared__ f32x2 fbT[32][9];                   // 2304 B (py,px for fallback)

    int tid = threadIdx.x;
    int wid = tid >> 6;
    int l   = tid & 63;
    int lr  = l & 15;
    int lg  = l >> 4;
    int mhalf = wid >> 1;
    int nhalf = wid & 1;

    // XCD-aware swizzle: nwg = 3200, 3200 % 8 == 0 -> bijective
    int bid = blockIdx.x;
    int g_blk = (bid & 7) * 400 + (bid >> 3);

    int pix_base = g_blk * 32;
    int b   = pix_base / HWp;
    int rem = pix_base - b * HWp;
    int y   = rem / Ww;
    int x0  = rem - y * Ww;            // multiple of 32, row-aligned

    const short* wTbF   = ws;
    const short* wToffF = ws + WTBF_SHORTS;
    const char*  xclb   = (const char*)(ws + XCL_OFS) + (size_t)b * HWp * 128;

    // ---------------- Phase 0: cooperative halo fill (coalesced) ----------
    for (int i = tid; i < HROWS * HCOLS * 8; i += 256) {
        int pl = i >> 3, cg2 = i & 7;
        int hy = pl / HCOLS, hx = pl - hy * HCOLS;
        int gy = y - 2 + hy, gx = x0 - 2 + hx;
        int4v v;
        if (gy >= 0 && gy < Hh && gx >= 0 && gx < Ww)
            v = *(const int4v*)(xclb + (size_t)(gy * Ww + gx) * 128 + cg2 * 16);
        else
            v = (int4v){0, 0, 0, 0};
        *(int4v*)(halo_s + pl * HPX + cg2 * 8) = v;
    }
    __syncthreads();

    // ---------------- Phase 1: offset GEMM, A from halo -------------------
    {
        // A short-offsets for the 9 integer taps of pixel (mhalf*16+lr)
        int hxb = mhalf * 16 + lr + 1;           // hx of tap tx=0
        int hoffA[9];
#pragma unroll
        for (int t = 0; t < 9; ++t) {
            int ty = t / 3, tx = t - ty * 3;
            hoffA[t] = (ty + 1) * HROWS_STRIDE + (hxb + tx) * HPX + lg * 8;
        }
        const short* wofr = wToffF + (size_t)nhalf * 512 + l * 8;
        f32x4 accA = {0.f, 0.f, 0.f, 0.f};
        f32x4 accB = {0.f, 0.f, 0.f, 0.f};
        f16x8 sB[4];
#pragma unroll
        for (int u = 0; u < 4; ++u)
            sB[u] = *(const f16x8*)(wofr + u * 1024);
        f16x8 sa2[2];
        sa2[0] = *(const f16x8*)(halo_s + hoffA[0]);
#pragma unroll
        for (int u = 0; u < 18; ++u) {
            const int s = u & 3;
            if (u + 1 < 18) {
                const int t2 = (u + 1) >> 1, h2 = (u + 1) & 1;
                sa2[(u + 1) & 1] = *(const f16x8*)(halo_s + hoffA[t2] + h2 * 32);
            }
            if (u & 1)
                accB = __builtin_amdgcn_mfma_f32_16x16x32_f16(sa2[u & 1], sB[s], accB, 0, 0, 0);
            else
                accA = __builtin_amdgcn_mfma_f32_16x16x32_f16(sa2[u & 1], sB[s], accA, 0, 0, 0);
            if (u + 4 < 18)
                sB[s] = *(const f16x8*)(wofr + (u + 4) * 1024);
            __builtin_amdgcn_sched_barrier(0);
        }
        int oc_row = nhalf * 16 + lr;
        if (oc_row < 18) {
            float bv = b_off[oc_row];
#pragma unroll
            for (int j = 0; j < 4; ++j)
                offbuf[mhalf * 16 + lg * 4 + j][oc_row] = accA[j] + accB[j] + bv;
        }
    }
    __syncthreads();

    // ---------------- Phase 2: tables (halo offsets + weights) ------------
    for (int i = tid; i < 288; i += 256) {
        int px = i / 9, tap = i - px * 9;
        int ty = tap / 3, tx = tap - ty * 3;
        f32x2 d2 = *(const f32x2*)&offbuf[px][2 * tap];
        float py  = (float)(y - 1 + ty) + d2[0];
        float pxf = (float)(x0 + px - 1 + tx) + d2[1];
        float fy = floorf(py), fx = floorf(pxf);
        float ly = py - fy, lx = pxf - fx;
        int iy0 = (int)fy, ix0 = (int)fx;
        int iy1 = iy0 + 1, ix1 = ix0 + 1;
        bool vy0 = (iy0 >= 0) && (iy0 < Hh);
        bool vy1 = (iy1 >= 0) && (iy1 < Hh);
        bool vx0 = (ix0 >= 0) && (ix0 < Ww);
        bool vx1 = (ix1 >= 0) && (ix1 < Ww);
        float w00 = (vy0 && vx0) ? (1.f - ly) * (1.f - lx) : 0.f;
        float w01 = (vy0 && vx1) ? (1.f - ly) * lx         : 0.f;
        float w10 = (vy1 && vx0) ? ly * (1.f - lx)         : 0.f;
        float w11 = (vy1 && vx1) ? ly * lx                 : 0.f;
        int hy = iy0 - (y - 2);
        int hx = ix0 - (x0 - 2);
        bool inH = (hy >= 0) && (hy <= HROWS - 2) && (hx >= 0) && (hx <= HCOLS - 2);
        hofT[px][tap] = inH ? (hy * HROWS_STRIDE + hx * HPX) : -1;
        wgtT[px][tap] = (f16x4){(_Float16)w00, (_Float16)w01,
                                (_Float16)w10, (_Float16)w11};
        fbT[px][tap]  = (f32x2){py, pxf};
    }
    __syncthreads();

    // ---------------- Phase 3: main GEMM, A from halo ---------------------
    f32x4 acc[2];
    acc[0] = (f32x4){0.f, 0.f, 0.f, 0.f};
    acc[1] = (f32x4){0.f, 0.f, 0.f, 0.f};
    int px_t = mhalf * 16 + lr;
    const short* wfb = wTbF + (size_t)nhalf * 1024 + l * 8;
    f16x8 sB0[4], sB1[4];
#pragma unroll
    for (int u = 0; u < 4; ++u) {
        sB0[u] = *(const f16x8*)(wfb + u * 2048);
        sB1[u] = *(const f16x8*)(wfb + u * 2048 + 512);
    }
#pragma unroll
    for (int t = 0; t < 9; ++t) {
        int ho = hofT[px_t][t];
        f16x4 wg = wgtT[px_t][t];
        int hoS = max(ho, 0);
        const short* q0 = halo_s + hoS + lg * 8;
#pragma unroll
        for (int h = 0; h < 2; ++h) {
            const int u = t * 2 + h, s = u & 3;
            const short* q = q0 + h * 32;
            f16x8 c00 = *(const f16x8*)(q);
            f16x8 c01 = *(const f16x8*)(q + HPX);
            f16x8 c10 = *(const f16x8*)(q + HROWS_STRIDE);
            f16x8 c11 = *(const f16x8*)(q + HROWS_STRIDE + HPX);
            f16x8 a = c00 * vsplat(wg[0]) + c01 * vsplat(wg[1])
                    + c10 * vsplat(wg[2]) + c11 * vsplat(wg[3]);
            if (ho < 0) {   // rare out-of-halo fallback (|offset| > ~1)
                f32x2 pq = fbT[px_t][t];
                float fy = floorf(pq[0]), fx = floorf(pq[1]);
                int iy0 = (int)fy, ix0 = (int)fx;
                int cy0 = min(max(iy0, 0), Hh - 1), cy1 = min(max(iy0 + 1, 0), Hh - 1);
                int cx0 = min(max(ix0, 0), Ww - 1), cx1 = min(max(ix0 + 1, 0), Ww - 1);
                int cbh = h * 64 + lg * 16;
                f16x8 g00 = *(const f16x8*)(xclb + (size_t)(cy0 * Ww + cx0) * 128 + cbh);
                f16x8 g01 = *(const f16x8*)(xclb + (size_t)(cy0 * Ww + cx1) * 128 + cbh);
                f16x8 g10 = *(const f16x8*)(xclb + (size_t)(cy1 * Ww + cx0) * 128 + cbh);
                f16x8 g11 = *(const f16x8*)(xclb + (size_t)(cy1 * Ww + cx1) * 128 + cbh);
                a = g00 * vsplat(wg[0]) + g01 * vsplat(wg[1])
                  + g10 * vsplat(wg[2]) + g11 * vsplat(wg[3]);
            }
            acc[0] = __builtin_amdgcn_mfma_f32_16x16x32_f16(a, sB0[s], acc[0], 0, 0, 0);
            acc[1] = __builtin_amdgcn_mfma_f32_16x16x32_f16(a, sB1[s], acc[1], 0, 0, 0);
            if (u + 4 < 18) {
                sB0[s] = *(const f16x8*)(wfb + (u + 4) * 2048);
                sB1[s] = *(const f16x8*)(wfb + (u + 4) * 2048 + 512);
            }
            __builtin_amdgcn_sched_barrier(0);
        }
    }

    // ---------------- Epilogue ----------------
    float* obase = out + (size_t)b * COUTc * HWp + y * Ww + x0;
#pragma unroll
    for (int nt = 0; nt < 2; ++nt) {
        int o = nhalf * 32 + nt * 16 + lr;
        float bv = bias[o];
#pragma unroll
        for (int j = 0; j < 4; ++j)
            obase[(size_t)o * HWp + mhalf * 16 + lg * 4 + j] = acc[nt][j] + bv;
    }
}

// ---------------------------------------------------------------------------
extern "C" void kernel_launch(void* const* d_in, const int* in_sizes, int n_in,
                              void* d_out, int out_size, void* d_ws, size_t ws_size,
                              hipStream_t stream) {
    const float* x      = (const float*)d_in[0];
    const float* w_off  = (const float*)d_in[1];
    const float* b_off  = (const float*)d_in[2];
    const float* weight = (const float*)d_in[3];
    const float* bias   = (const float*)d_in[4];
    float* outp = (float*)d_out;
    short* ws   = (short*)d_ws;

    // 400 blocks xcl + 144 blocks weights + 1 block zero pad
    prep_all<<<545, 256, 0, stream>>>(x, weight, w_off, ws);

    int nblocks = (Bq * HWp) / 32;   // 3200 workgroups, 32 pixels each
    fused_cl<<<nblocks, 256, 0, stream>>>(ws, b_off, bias, outp);
}